// Round 8
// baseline (142.758 us; speedup 1.0000x reference)
//
#include <hip/hip_runtime.h>
#include <math.h>

#define NB  32
#define NKC 128
#define DH  64
#define NEX 1024
#define G3  192

// ws layout (floats)
#define XOFF    0         // 32*64   = 2048
#define KCIOFF  2048      // 32*128  = 4096
#define EPOFF   6144      // 128*64  = 8192  (b-independent, computed in k0)
#define NHOFF   14336     // 32*128*64 = 262144   [b][i][d]
#define DPOFF   276480    // 32*64*128 = 262144   [b][d][i]  (TRANSPOSED)

__device__ __forceinline__ float sigf(float x) { return 1.0f / (1.0f + expf(-x)); }
__device__ __forceinline__ float dot4(float4 a, float4 b) {
    return fmaf(a.x, b.x, fmaf(a.y, b.y, fmaf(a.z, b.z, a.w * b.w)));
}

// ---------------------------------------------------------------------------
// k0: x (blocks 0..255) + epart (256..259, b-independent). 256 threads.
// ---------------------------------------------------------------------------
__global__ __launch_bounds__(256) void k0_x(
    const float* __restrict__ ex, const float* __restrict__ su,
    const float* __restrict__ W_ex, const float* __restrict__ W_kc,
    const float* __restrict__ fpart_w, const float* __restrict__ fpart_b,
    float* __restrict__ ws)
{
    int t = threadIdx.x, wave = t >> 6, lane = t & 63;
    __shared__ __align__(16) float fw68[64 * 68];
    __shared__ __align__(16) float wkT[32 * 68];

    if (blockIdx.x < 256) {
        int b = blockIdx.x >> 3;
        int dbase = (blockIdx.x & 7) * 8;
        float sub = su[b];
        const float* exb = ex + (size_t)b * NEX;
        float er[16];
        #pragma unroll
        for (int i = 0; i < 16; ++i) er[i] = exb[lane + i * 64];
        #pragma unroll
        for (int p = 0; p < 2; ++p) {
            int d = dbase + wave * 2 + p;
            const float* wr = W_ex + (size_t)d * (2 * NEX);
            float a1 = 0.f, a2 = 0.f;
            #pragma unroll
            for (int i = 0; i < 16; ++i) {
                int k = lane + i * 64;
                a1 = fmaf(er[i], wr[k], a1);
                a2 = fmaf(er[i], wr[NEX + k], a2);
            }
            float v = sub * a1 + (1.0f - sub) * a2;
            #pragma unroll
            for (int off = 32; off; off >>= 1) v += __shfl_down(v, off, 64);
            if (lane == 0) ws[XOFF + b * DH + d] = v;
        }
    } else {
        // epart[j,d] = fpart_b[d] + sum_c W_kc[c,j] * fpart_w[d,64+c]
        int eb = blockIdx.x - 256;           // 0..3, 32 j each
        for (int idx = t; idx < 64 * 16; idx += 256) {
            int d = idx >> 4, q = idx & 15;
            *(float4*)&fw68[d * 68 + 4 * q] =
                *(const float4*)&fpart_w[d * 128 + 64 + 4 * q];
        }
        for (int idx = t; idx < 2048; idx += 256) {
            int c = idx >> 5, jl = idx & 31;
            wkT[jl * 68 + c] = W_kc[(size_t)c * NKC + eb * 32 + jl];
        }
        __syncthreads();
        #pragma unroll
        for (int r = 0; r < 8; ++r) {
            int idx = t + r * 256;
            int jl = idx >> 6, d = idx & 63;
            float a = fpart_b[d];
            #pragma unroll
            for (int q = 0; q < 16; ++q) {
                float4 fv = *(float4*)&fw68[d * 68 + 4 * q];
                float4 wv = *(float4*)&wkT[jl * 68 + 4 * q];
                a += dot4(fv, wv);
            }
            ws[EPOFF + (eb * 32 + jl) * DH + d] = a;
        }
    }
}

// ---------------------------------------------------------------------------
// k1: kci + gi + tgru + new_h + dpart(transposed). 256 blocks x 256 threads
// (4 waves, m=4 i/wave, 2 blocks/CU). Row-major stride-36 weight LDS.
// ---------------------------------------------------------------------------
__global__ __launch_bounds__(256) void k1_tgru(
    const float* __restrict__ h, const float* __restrict__ ex,
    const float* __restrict__ ex_graph,
    const float* __restrict__ tgru_wih, const float* __restrict__ tgru_whh,
    const float* __restrict__ tgru_bih, const float* __restrict__ tgru_bhh,
    const float* __restrict__ fpart_w, float* __restrict__ ws)
{
    int t = threadIdx.x, wave = t >> 6, lane = t & 63;
    int b = blockIdx.x >> 3;
    int i0 = (blockIdx.x & 7) * 16;

    __shared__ __align__(16) float whh36[G3 * 36];  // reused: fw68 (64*68)
    __shared__ __align__(16) float wih36[G3 * 36];  // reused: dptT (64*17)
    __shared__ __align__(16) float ht[16 * DH];
    __shared__ __align__(16) float dlt[16 * DH];
    __shared__ __align__(16) float xs[DH];
    __shared__ float kred[256];
    __shared__ float gis[G3];
    __shared__ float bhh3[G3];
    __shared__ float kciL[16];

    // kci partials FIRST (longest-latency strided loads): 16 slices of 64 k
    {
        int i = t & 15, ks = t >> 4, kb = ks * 64;
        const float* exb = ex + (size_t)b * NEX;
        const float* eg = ex_graph + i0 + i;
        float a = 0.f;
        #pragma unroll 4
        for (int k = 0; k < 64; ++k)
            a = fmaf(exb[kb + k], eg[(size_t)(kb + k) * NKC], a);
        kred[t] = a;
    }
    {
        const float* hb = h + (size_t)(b * NKC + i0) * DH;
        *(float4*)&ht[t * 4] = *(const float4*)&hb[t * 4];
    }
    if (t < DH) xs[t] = ws[XOFF + b * DH + t];
    if (t < G3) bhh3[t] = tgru_bhh[t];
    __syncthreads();
    if (t < 16) {
        float s = 0.f;
        #pragma unroll
        for (int r = 0; r < 16; ++r) s += kred[r * 16 + t];
        kciL[t] = s;
        ws[KCIOFF + b * NKC + i0 + t] = s;
    }

    float giA = (t < G3) ? tgru_bih[t] : 0.f;
    float ar[4], az[4], an[4];
    #pragma unroll
    for (int m = 0; m < 4; ++m) {
        ar[m] = bhh3[lane]; az[m] = bhh3[64 + lane]; an[m] = bhh3[128 + lane];
    }
    for (int ch = 0; ch < 2; ++ch) {
        __syncthreads();
        for (int idx = t; idx < G3 * 8; idx += 256) {
            int row = idx >> 3, q = idx & 7;
            *(float4*)&whh36[row * 36 + 4 * q] =
                *(const float4*)&tgru_whh[row * DH + ch * 32 + 4 * q];
            *(float4*)&wih36[row * 36 + 4 * q] =
                *(const float4*)&tgru_wih[row * DH + ch * 32 + 4 * q];
        }
        __syncthreads();
        if (t < G3) {   // gi partial (wave-uniform: waves 0-2)
            #pragma unroll
            for (int q = 0; q < 8; ++q) {
                float4 wv = *(float4*)&wih36[t * 36 + 4 * q];
                float4 xv = *(float4*)&xs[ch * 32 + 4 * q];
                giA += dot4(wv, xv);
            }
        }
        #pragma unroll
        for (int q = 0; q < 8; ++q) {
            float4 wr = *(float4*)&whh36[lane * 36 + 4 * q];
            float4 wz = *(float4*)&whh36[(64 + lane) * 36 + 4 * q];
            float4 wn = *(float4*)&whh36[(128 + lane) * 36 + 4 * q];
            int kb = ch * 32 + 4 * q;
            #pragma unroll
            for (int m = 0; m < 4; ++m) {
                float4 hk = *(float4*)&ht[(wave * 4 + m) * DH + kb];  // bcast
                ar[m] += dot4(wr, hk);
                az[m] += dot4(wz, hk);
                an[m] += dot4(wn, hk);
            }
        }
    }
    if (t < G3) gis[t] = giA;
    __syncthreads();
    // GRU epilogue per i
    #pragma unroll
    for (int m = 0; m < 4; ++m) {
        int il = wave * 4 + m;
        float hval = ht[il * DH + lane];
        float r = sigf(gis[lane] + ar[m]);
        float z = sigf(gis[64 + lane] + az[m]);
        float n = tanhf(gis[128 + lane] + r * an[m]);
        float th = (1.0f - z) * n + z * hval;
        float kv = kciL[il];
        float nh = (1.0f - kv) * hval + kv * th;
        ws[NHOFF + (size_t)(b * NKC + i0 + il) * DH + lane] = nh;
        dlt[il * DH + lane] = kv * (th - hval);
    }
    __syncthreads();
    // dpart = delta_h @ fpart_w[:, :64].T ; fw68[d*68+k] rows
    float* fw68 = whh36;   // 64*68 = 4352
    for (int idx = t; idx < 64 * 16; idx += 256) {
        int d = idx >> 4, q = idx & 15;
        *(float4*)&fw68[d * 68 + 4 * q] = *(const float4*)&fpart_w[d * 128 + 4 * q];
    }
    __syncthreads();
    float acc[4] = {0.f, 0.f, 0.f, 0.f};
    #pragma unroll
    for (int q = 0; q < 16; ++q) {
        float4 w = *(float4*)&fw68[lane * 68 + 4 * q];
        #pragma unroll
        for (int m = 0; m < 4; ++m) {
            float4 dv = *(float4*)&dlt[(wave * 4 + m) * DH + 4 * q];  // bcast
            acc[m] += dot4(w, dv);
        }
    }
    // transpose in LDS (stride 17), coalesced global write [b][d][i]
    float* dptT = wih36;   // 64*17 = 1088
    __syncthreads();
    #pragma unroll
    for (int m = 0; m < 4; ++m) dptT[lane * 17 + wave * 4 + m] = acc[m];
    __syncthreads();
    for (int idx = t; idx < 1024; idx += 256) {
        int d = idx >> 4, il = idx & 15;
        ws[DPOFF + (size_t)b * 8192 + d * NKC + i0 + il] = dptT[d * 17 + il];
    }
}

// ---------------------------------------------------------------------------
// kB: partj + outj + kcj + ugru + h_out. 256 blocks x 256 threads (4 waves,
// m=4 j/wave, 2 blocks/CU). epart loaded from ws. All hot LDS reads b128.
// ---------------------------------------------------------------------------
__global__ __launch_bounds__(256) void kB_update(
    const float* __restrict__ kc_gamma,
    const float* __restrict__ ulin_w, const float* __restrict__ ulin_b,
    const float* __restrict__ ugru_wih, const float* __restrict__ ugru_whh,
    const float* __restrict__ ugru_bih, const float* __restrict__ ugru_bhh,
    float* __restrict__ ws, float* __restrict__ out)
{
    int t = threadIdx.x, wave = t >> 6, lane = t & 63;
    int b = blockIdx.x >> 3;
    int j0 = (blockIdx.x & 7) * 16;

    __shared__ __align__(16) float scratch[13824];
    __shared__ __align__(16) float pjS[1024];
    __shared__ __align__(16) float outjS[1024];
    __shared__ __align__(16) float newhS[1024];
    __shared__ __align__(16) float epS[1024];
    __shared__ float kciF[NKC];
    __shared__ float kcjS[16];
    __shared__ float bihS[G3];
    __shared__ float bhhS[G3];

    float* dpT = scratch;             // 64*132 = 8448   [d][i]
    float* wjT = scratch + 8448;      // 16*132 = 2112   [jl][i]

    // stage dpart (global [d][i] coalesced -> LDS stride-132 rows)
    const float* dp = ws + DPOFF + (size_t)b * 8192;
    #pragma unroll
    for (int r = 0; r < 8; ++r) {
        int idx4 = t + r * 256;
        int d = idx4 >> 5, qi = idx4 & 31;
        *(float4*)&dpT[d * 132 + 4 * qi] = *(const float4*)&dp[d * NKC + 4 * qi];
    }
    *(float4*)&epS[t * 4]   = *(const float4*)&ws[EPOFF + j0 * DH + t * 4];
    *(float4*)&newhS[t * 4] =
        *(const float4*)&ws[NHOFF + (size_t)(b * NKC + j0) * DH + t * 4];
    if (t < NKC) kciF[t] = ws[KCIOFF + b * NKC + t];
    if (t < G3) { bihS[t] = ugru_bih[t]; bhhS[t] = ugru_bhh[t]; }
    __syncthreads();
    // wj transposed [jl][i], stride 132
    for (int idx = t; idx < 2048; idx += 256) {
        int i = idx >> 4, jl = idx & 15;
        wjT[jl * 132 + i] = kciF[i] * sigf(kc_gamma[i * NKC + j0 + jl]);
    }
    __syncthreads();
    if (t < 16) {
        float s = 0.f;
        #pragma unroll
        for (int qi = 0; qi < 32; ++qi) {
            float4 v = *(float4*)&wjT[t * 132 + 4 * qi];
            s += v.x + v.y + v.z + v.w;
        }
        kcjS[t] = s;
    }
    // partj: b128 dv (own row, amortized over 4 j) + b128 wj broadcast
    float ep[4], pa[4];
    #pragma unroll
    for (int m = 0; m < 4; ++m) {
        ep[m] = epS[(wave * 4 + m) * DH + lane]; pa[m] = 0.f;
    }
    for (int qi = 0; qi < 32; ++qi) {
        float4 dv = *(float4*)&dpT[lane * 132 + 4 * qi];
        #pragma unroll
        for (int m = 0; m < 4; ++m) {
            float4 wv = *(float4*)&wjT[(wave * 4 + m) * 132 + 4 * qi];  // bcast
            pa[m] = fmaf(fmaxf(dv.x + ep[m], 0.f), wv.x, pa[m]);
            pa[m] = fmaf(fmaxf(dv.y + ep[m], 0.f), wv.y, pa[m]);
            pa[m] = fmaf(fmaxf(dv.z + ep[m], 0.f), wv.z, pa[m]);
            pa[m] = fmaf(fmaxf(dv.w + ep[m], 0.f), wv.w, pa[m]);
        }
    }
    #pragma unroll
    for (int m = 0; m < 4; ++m) pjS[(wave * 4 + m) * DH + lane] = pa[m];
    __syncthreads();
    // outj = relu(pj @ ulin_w.T + b); ul68[d][k] rows over dead dpT
    float* ul68 = scratch;            // 64*68 = 4352
    for (int idx = t; idx < 64 * 16; idx += 256) {
        int d = idx >> 4, q = idx & 15;
        *(float4*)&ul68[d * 68 + 4 * q] = *(const float4*)&ulin_w[d * DH + 4 * q];
    }
    float ulb = ulin_b[lane];
    __syncthreads();
    float oa[4] = {ulb, ulb, ulb, ulb};
    #pragma unroll
    for (int q = 0; q < 16; ++q) {
        float4 uv = *(float4*)&ul68[lane * 68 + 4 * q];
        #pragma unroll
        for (int m = 0; m < 4; ++m) {
            float4 pv = *(float4*)&pjS[(wave * 4 + m) * DH + 4 * q];  // bcast
            oa[m] += dot4(uv, pv);
        }
    }
    #pragma unroll
    for (int m = 0; m < 4; ++m)
        outjS[(wave * 4 + m) * DH + lane] = fmaxf(oa[m], 0.f);
    // ugru: k-chunked row-major stride-36 weights
    float* wih36 = scratch;           // 192*36 = 6912
    float* whh36 = scratch + 6912;    // 192*36 = 6912
    float gir[4], giz[4], gin[4], ghr[4], ghz[4], ghn[4];
    #pragma unroll
    for (int m = 0; m < 4; ++m)
        gir[m] = giz[m] = gin[m] = ghr[m] = ghz[m] = ghn[m] = 0.f;
    for (int ch = 0; ch < 2; ++ch) {
        __syncthreads();   // covers ul68/outjS deps
        for (int idx = t; idx < G3 * 8; idx += 256) {
            int row = idx >> 3, q = idx & 7;
            *(float4*)&wih36[row * 36 + 4 * q] =
                *(const float4*)&ugru_wih[row * DH + ch * 32 + 4 * q];
            *(float4*)&whh36[row * 36 + 4 * q] =
                *(const float4*)&ugru_whh[row * DH + ch * 32 + 4 * q];
        }
        __syncthreads();
        #pragma unroll
        for (int q = 0; q < 8; ++q) {
            float4 wir = *(float4*)&wih36[lane * 36 + 4 * q];
            float4 wiz = *(float4*)&wih36[(64 + lane) * 36 + 4 * q];
            float4 win = *(float4*)&wih36[(128 + lane) * 36 + 4 * q];
            float4 wwr = *(float4*)&whh36[lane * 36 + 4 * q];
            float4 wwz = *(float4*)&whh36[(64 + lane) * 36 + 4 * q];
            float4 wwn = *(float4*)&whh36[(128 + lane) * 36 + 4 * q];
            int kb = ch * 32 + 4 * q;
            #pragma unroll
            for (int m = 0; m < 4; ++m) {
                int jl = wave * 4 + m;
                float4 ov = *(float4*)&outjS[jl * DH + kb];  // bcast
                float4 nv = *(float4*)&newhS[jl * DH + kb];  // bcast
                gir[m] += dot4(wir, ov);
                giz[m] += dot4(wiz, ov);
                gin[m] += dot4(win, ov);
                ghr[m] += dot4(wwr, nv);
                ghz[m] += dot4(wwz, nv);
                ghn[m] += dot4(wwn, nv);
            }
        }
    }
    #pragma unroll
    for (int m = 0; m < 4; ++m) {
        int jl = wave * 4 + m;
        float r = sigf(gir[m] + bihS[lane] + ghr[m] + bhhS[lane]);
        float z = sigf(giz[m] + bihS[64 + lane] + ghz[m] + bhhS[64 + lane]);
        float n = tanhf(gin[m] + bihS[128 + lane] + r * (ghn[m] + bhhS[128 + lane]));
        float nh = newhS[jl * DH + lane];
        float uh = (1.0f - z) * n + z * nh;
        float kj = kcjS[jl];
        out[(size_t)(b * NKC + j0 + jl) * DH + lane] = (1.0f - kj) * nh + kj * uh;
    }
}

extern "C" void kernel_launch(void* const* d_in, const int* in_sizes, int n_in,
                              void* d_out, int out_size, void* d_ws, size_t ws_size,
                              hipStream_t stream) {
    const float* h        = (const float*)d_in[0];
    const float* ex       = (const float*)d_in[1];
    const float* su       = (const float*)d_in[2];
    const float* ex_graph = (const float*)d_in[3];
    const float* kc_gamma = (const float*)d_in[4];
    const float* W_ex     = (const float*)d_in[5];
    const float* W_kc     = (const float*)d_in[6];
    const float* tgru_wih = (const float*)d_in[7];
    const float* tgru_whh = (const float*)d_in[8];
    const float* tgru_bih = (const float*)d_in[9];
    const float* tgru_bhh = (const float*)d_in[10];
    const float* fpart_w  = (const float*)d_in[11];
    const float* fpart_b  = (const float*)d_in[12];
    const float* ulin_w   = (const float*)d_in[13];
    const float* ulin_b   = (const float*)d_in[14];
    const float* ugru_wih = (const float*)d_in[15];
    const float* ugru_whh = (const float*)d_in[16];
    const float* ugru_bih = (const float*)d_in[17];
    const float* ugru_bhh = (const float*)d_in[18];
    float* ws  = (float*)d_ws;
    float* out = (float*)d_out;

    hipLaunchKernelGGL(k0_x, dim3(260), dim3(256), 0, stream,
                       ex, su, W_ex, W_kc, fpart_w, fpart_b, ws);
    hipLaunchKernelGGL(k1_tgru, dim3(256), dim3(256), 0, stream,
                       h, ex, ex_graph, tgru_wih, tgru_whh, tgru_bih,
                       tgru_bhh, fpart_w, ws);
    hipLaunchKernelGGL(kB_update, dim3(256), dim3(256), 0, stream,
                       kc_gamma, ulin_w, ulin_b,
                       ugru_wih, ugru_whh, ugru_bih, ugru_bhh, ws, out);
}

// Round 9
// 132.750 us; speedup vs baseline: 1.0754x; 1.0754x over previous
//
#include <hip/hip_runtime.h>
#include <math.h>

#define NB  32
#define NKC 128
#define DH  64
#define NEX 1024
#define G3  192

// ws layout (floats)
#define XOFF    0         // 32*64   = 2048
#define KCIOFF  2048      // 32*128  = 4096
#define EPOFF   6144      // 128*64  = 8192  (b-independent, computed in k0)
#define NHOFF   14336     // 32*128*64 = 262144   [b][i][d]
#define DPOFF   276480    // 32*64*128 = 262144   [b][d][i]  (TRANSPOSED)

__device__ __forceinline__ float sigf(float x) { return 1.0f / (1.0f + expf(-x)); }
__device__ __forceinline__ float dot4(float4 a, float4 b) {
    return fmaf(a.x, b.x, fmaf(a.y, b.y, fmaf(a.z, b.z, a.w * b.w)));
}

// ---------------------------------------------------------------------------
// k0: x (blocks 0..255) + epart (256..259, b-independent). 256 threads.
// ---------------------------------------------------------------------------
__global__ __launch_bounds__(256) void k0_x(
    const float* __restrict__ ex, const float* __restrict__ su,
    const float* __restrict__ W_ex, const float* __restrict__ W_kc,
    const float* __restrict__ fpart_w, const float* __restrict__ fpart_b,
    float* __restrict__ ws)
{
    int t = threadIdx.x, wave = t >> 6, lane = t & 63;
    __shared__ __align__(16) float fw68[64 * 68];
    __shared__ __align__(16) float wkT[32 * 68];

    if (blockIdx.x < 256) {
        int b = blockIdx.x >> 3;
        int dbase = (blockIdx.x & 7) * 8;
        float sub = su[b];
        const float* exb = ex + (size_t)b * NEX;
        float er[16];
        #pragma unroll
        for (int i = 0; i < 16; ++i) er[i] = exb[lane + i * 64];
        #pragma unroll
        for (int p = 0; p < 2; ++p) {
            int d = dbase + wave * 2 + p;
            const float* wr = W_ex + (size_t)d * (2 * NEX);
            float a1 = 0.f, a2 = 0.f;
            #pragma unroll
            for (int i = 0; i < 16; ++i) {
                int k = lane + i * 64;
                a1 = fmaf(er[i], wr[k], a1);
                a2 = fmaf(er[i], wr[NEX + k], a2);
            }
            float v = sub * a1 + (1.0f - sub) * a2;
            #pragma unroll
            for (int off = 32; off; off >>= 1) v += __shfl_down(v, off, 64);
            if (lane == 0) ws[XOFF + b * DH + d] = v;
        }
    } else {
        // epart[j,d] = fpart_b[d] + sum_c W_kc[c,j] * fpart_w[d,64+c]
        int eb = blockIdx.x - 256;           // 0..3, 32 j each
        for (int idx = t; idx < 64 * 16; idx += 256) {
            int d = idx >> 4, q = idx & 15;
            *(float4*)&fw68[d * 68 + 4 * q] =
                *(const float4*)&fpart_w[d * 128 + 64 + 4 * q];
        }
        for (int idx = t; idx < 2048; idx += 256) {
            int c = idx >> 5, jl = idx & 31;
            wkT[jl * 68 + c] = W_kc[(size_t)c * NKC + eb * 32 + jl];
        }
        __syncthreads();
        #pragma unroll
        for (int r = 0; r < 8; ++r) {
            int idx = t + r * 256;
            int jl = idx >> 6, d = idx & 63;
            float a = fpart_b[d];
            #pragma unroll
            for (int q = 0; q < 16; ++q) {
                float4 fv = *(float4*)&fw68[d * 68 + 4 * q];
                float4 wv = *(float4*)&wkT[jl * 68 + 4 * q];
                a += dot4(fv, wv);
            }
            ws[EPOFF + (eb * 32 + jl) * DH + d] = a;
        }
    }
}

// ---------------------------------------------------------------------------
// k1: kci + gi + tgru + new_h + dpart(transposed). 256 blocks x 512 threads
// (round-7 config: 8 waves, m=2). Row-major stride-36 weight LDS -> b128.
// ---------------------------------------------------------------------------
__global__ __launch_bounds__(512) void k1_tgru(
    const float* __restrict__ h, const float* __restrict__ ex,
    const float* __restrict__ ex_graph,
    const float* __restrict__ tgru_wih, const float* __restrict__ tgru_whh,
    const float* __restrict__ tgru_bih, const float* __restrict__ tgru_bhh,
    const float* __restrict__ fpart_w, float* __restrict__ ws)
{
    int t = threadIdx.x, wave = t >> 6, lane = t & 63;
    int b = blockIdx.x >> 3;
    int i0 = (blockIdx.x & 7) * 16;

    __shared__ __align__(16) float whh36[G3 * 36];  // reused: fw68 (64*68)
    __shared__ __align__(16) float wih36[G3 * 36];  // reused: dptT (64*17)
    __shared__ __align__(16) float ht[16 * DH];
    __shared__ __align__(16) float dlt[16 * DH];
    __shared__ __align__(16) float xs[DH];
    __shared__ float kred[512];
    __shared__ float gis[G3];
    __shared__ float bhh3[G3];
    __shared__ float kciL[16];

    // kci partials FIRST (longest-latency strided loads): 32 slices of 32 k
    {
        int i = t & 15, ks = t >> 4, kb = ks * 32;
        const float* exb = ex + (size_t)b * NEX;
        const float* eg = ex_graph + i0 + i;
        float a = 0.f;
        #pragma unroll 4
        for (int k = 0; k < 32; ++k)
            a = fmaf(exb[kb + k], eg[(size_t)(kb + k) * NKC], a);
        kred[t] = a;
    }
    const float* hb = h + (size_t)(b * NKC + i0) * DH;
    for (int idx = t; idx < 16 * DH; idx += 512) ht[idx] = hb[idx];
    if (t < DH) xs[t] = ws[XOFF + b * DH + t];
    if (t < G3) bhh3[t] = tgru_bhh[t];
    __syncthreads();
    if (t < 16) {
        float s = 0.f;
        #pragma unroll
        for (int r = 0; r < 32; ++r) s += kred[r * 16 + t];
        kciL[t] = s;
        ws[KCIOFF + b * NKC + i0 + t] = s;
    }

    float giA = (t < G3) ? tgru_bih[t] : 0.f;
    float ar[2], az[2], an[2];
    #pragma unroll
    for (int m = 0; m < 2; ++m) {
        ar[m] = bhh3[lane]; az[m] = bhh3[64 + lane]; an[m] = bhh3[128 + lane];
    }
    for (int ch = 0; ch < 2; ++ch) {
        __syncthreads();
        for (int idx = t; idx < G3 * 8; idx += 512) {
            int row = idx >> 3, q = idx & 7;
            *(float4*)&whh36[row * 36 + 4 * q] =
                *(const float4*)&tgru_whh[row * DH + ch * 32 + 4 * q];
            *(float4*)&wih36[row * 36 + 4 * q] =
                *(const float4*)&tgru_wih[row * DH + ch * 32 + 4 * q];
        }
        __syncthreads();
        if (t < G3) {   // gi partial (wave-uniform: waves 0-2)
            #pragma unroll
            for (int q = 0; q < 8; ++q) {
                float4 wv = *(float4*)&wih36[t * 36 + 4 * q];
                float4 xv = *(float4*)&xs[ch * 32 + 4 * q];
                giA += dot4(wv, xv);
            }
        }
        #pragma unroll
        for (int q = 0; q < 8; ++q) {
            float4 wr = *(float4*)&whh36[lane * 36 + 4 * q];
            float4 wz = *(float4*)&whh36[(64 + lane) * 36 + 4 * q];
            float4 wn = *(float4*)&whh36[(128 + lane) * 36 + 4 * q];
            int kb = ch * 32 + 4 * q;
            #pragma unroll
            for (int m = 0; m < 2; ++m) {
                float4 hk = *(float4*)&ht[(wave * 2 + m) * DH + kb];  // bcast
                ar[m] += dot4(wr, hk);
                az[m] += dot4(wz, hk);
                an[m] += dot4(wn, hk);
            }
        }
    }
    if (t < G3) gis[t] = giA;
    __syncthreads();
    // GRU epilogue per i
    #pragma unroll
    for (int m = 0; m < 2; ++m) {
        int il = wave * 2 + m;
        float hval = ht[il * DH + lane];
        float r = sigf(gis[lane] + ar[m]);
        float z = sigf(gis[64 + lane] + az[m]);
        float n = tanhf(gis[128 + lane] + r * an[m]);
        float th = (1.0f - z) * n + z * hval;
        float kv = kciL[il];
        float nh = (1.0f - kv) * hval + kv * th;
        ws[NHOFF + (size_t)(b * NKC + i0 + il) * DH + lane] = nh;
        dlt[il * DH + lane] = kv * (th - hval);
    }
    __syncthreads();
    // dpart = delta_h @ fpart_w[:, :64].T ; fw68[d*68+k] rows
    float* fw68 = whh36;   // 64*68 = 4352
    for (int idx = t; idx < 64 * 16; idx += 512) {
        int d = idx >> 4, q = idx & 15;
        *(float4*)&fw68[d * 68 + 4 * q] = *(const float4*)&fpart_w[d * 128 + 4 * q];
    }
    __syncthreads();
    float acc[2] = {0.f, 0.f};
    #pragma unroll
    for (int q = 0; q < 16; ++q) {
        float4 w = *(float4*)&fw68[lane * 68 + 4 * q];
        #pragma unroll
        for (int m = 0; m < 2; ++m) {
            float4 dv = *(float4*)&dlt[(wave * 2 + m) * DH + 4 * q];  // bcast
            acc[m] += dot4(w, dv);
        }
    }
    // transpose in LDS (stride 17), coalesced global write [b][d][i]
    float* dptT = wih36;   // 64*17 = 1088
    __syncthreads();
    #pragma unroll
    for (int m = 0; m < 2; ++m) dptT[lane * 17 + wave * 2 + m] = acc[m];
    __syncthreads();
    for (int idx = t; idx < 1024; idx += 512) {
        int d = idx >> 4, il = idx & 15;
        ws[DPOFF + (size_t)b * 8192 + d * NKC + i0 + il] = dptT[d * 17 + il];
    }
}

// ---------------------------------------------------------------------------
// kB: partj + outj + kcj + ugru + h_out. 256 blocks x 512 threads (round-7
// config). epart loaded from ws (hoisted to k0). All hot LDS reads b128.
// ---------------------------------------------------------------------------
__global__ __launch_bounds__(512) void kB_update(
    const float* __restrict__ kc_gamma,
    const float* __restrict__ ulin_w, const float* __restrict__ ulin_b,
    const float* __restrict__ ugru_wih, const float* __restrict__ ugru_whh,
    const float* __restrict__ ugru_bih, const float* __restrict__ ugru_bhh,
    float* __restrict__ ws, float* __restrict__ out)
{
    int t = threadIdx.x, wave = t >> 6, lane = t & 63;
    int b = blockIdx.x >> 3;
    int j0 = (blockIdx.x & 7) * 16;

    __shared__ __align__(16) float scratch[13824];
    __shared__ __align__(16) float pjS[1024];
    __shared__ __align__(16) float outjS[1024];
    __shared__ __align__(16) float newhS[1024];
    __shared__ __align__(16) float epS[1024];
    __shared__ float kciF[NKC];
    __shared__ float kcjS[16];
    __shared__ float bihS[G3];
    __shared__ float bhhS[G3];

    float* dpT = scratch;             // 64*132 = 8448   [d][i]
    float* wjT = scratch + 8448;      // 16*132 = 2112   [jl][i]

    // stage dpart (global [d][i] coalesced -> LDS stride-132 rows)
    const float* dp = ws + DPOFF + (size_t)b * 8192;
    #pragma unroll
    for (int r = 0; r < 4; ++r) {
        int idx4 = t + r * 512;
        int d = idx4 >> 5, qi = idx4 & 31;
        *(float4*)&dpT[d * 132 + 4 * qi] = *(const float4*)&dp[d * NKC + 4 * qi];
    }
    if (t < 256) {
        *(float4*)&epS[t * 4] = *(const float4*)&ws[EPOFF + j0 * DH + t * 4];
        *(float4*)&newhS[t * 4] =
            *(const float4*)&ws[NHOFF + (size_t)(b * NKC + j0) * DH + t * 4];
    }
    if (t < NKC) kciF[t] = ws[KCIOFF + b * NKC + t];
    if (t < G3) { bihS[t] = ugru_bih[t]; bhhS[t] = ugru_bhh[t]; }
    __syncthreads();
    // wj transposed [jl][i], stride 132
    for (int idx = t; idx < 2048; idx += 512) {
        int i = idx >> 4, jl = idx & 15;
        wjT[jl * 132 + i] = kciF[i] * sigf(kc_gamma[i * NKC + j0 + jl]);
    }
    __syncthreads();
    if (t < 16) {
        float s = 0.f;
        #pragma unroll
        for (int qi = 0; qi < 32; ++qi) {
            float4 v = *(float4*)&wjT[t * 132 + 4 * qi];
            s += v.x + v.y + v.z + v.w;
        }
        kcjS[t] = s;
    }
    // partj: b128 dv (own row) + b128 wj broadcast
    float ep[2], pa[2];
    #pragma unroll
    for (int m = 0; m < 2; ++m) {
        ep[m] = epS[(wave * 2 + m) * DH + lane]; pa[m] = 0.f;
    }
    for (int qi = 0; qi < 32; ++qi) {
        float4 dv = *(float4*)&dpT[lane * 132 + 4 * qi];
        #pragma unroll
        for (int m = 0; m < 2; ++m) {
            float4 wv = *(float4*)&wjT[(wave * 2 + m) * 132 + 4 * qi];  // bcast
            pa[m] = fmaf(fmaxf(dv.x + ep[m], 0.f), wv.x, pa[m]);
            pa[m] = fmaf(fmaxf(dv.y + ep[m], 0.f), wv.y, pa[m]);
            pa[m] = fmaf(fmaxf(dv.z + ep[m], 0.f), wv.z, pa[m]);
            pa[m] = fmaf(fmaxf(dv.w + ep[m], 0.f), wv.w, pa[m]);
        }
    }
    #pragma unroll
    for (int m = 0; m < 2; ++m) pjS[(wave * 2 + m) * DH + lane] = pa[m];
    __syncthreads();
    // outj = relu(pj @ ulin_w.T + b); ul68[d][k] rows over dead dpT
    float* ul68 = scratch;            // 64*68 = 4352
    for (int idx = t; idx < 64 * 16; idx += 512) {
        int d = idx >> 4, q = idx & 15;
        *(float4*)&ul68[d * 68 + 4 * q] = *(const float4*)&ulin_w[d * DH + 4 * q];
    }
    float ulb = ulin_b[lane];
    __syncthreads();
    float oa[2] = {ulb, ulb};
    #pragma unroll
    for (int q = 0; q < 16; ++q) {
        float4 uv = *(float4*)&ul68[lane * 68 + 4 * q];
        #pragma unroll
        for (int m = 0; m < 2; ++m) {
            float4 pv = *(float4*)&pjS[(wave * 2 + m) * DH + 4 * q];  // bcast
            oa[m] += dot4(uv, pv);
        }
    }
    #pragma unroll
    for (int m = 0; m < 2; ++m)
        outjS[(wave * 2 + m) * DH + lane] = fmaxf(oa[m], 0.f);
    // ugru: k-chunked row-major stride-36 weights, b128 everywhere
    float* wih36 = scratch;           // 192*36 = 6912
    float* whh36 = scratch + 6912;    // 192*36 = 6912
    float gir[2], giz[2], gin[2], ghr[2], ghz[2], ghn[2];
    #pragma unroll
    for (int m = 0; m < 2; ++m)
        gir[m] = giz[m] = gin[m] = ghr[m] = ghz[m] = ghn[m] = 0.f;
    for (int ch = 0; ch < 2; ++ch) {
        __syncthreads();   // covers ul68/outjS deps
        for (int idx = t; idx < G3 * 8; idx += 512) {
            int row = idx >> 3, q = idx & 7;
            *(float4*)&wih36[row * 36 + 4 * q] =
                *(const float4*)&ugru_wih[row * DH + ch * 32 + 4 * q];
            *(float4*)&whh36[row * 36 + 4 * q] =
                *(const float4*)&ugru_whh[row * DH + ch * 32 + 4 * q];
        }
        __syncthreads();
        #pragma unroll
        for (int q = 0; q < 8; ++q) {
            float4 wir = *(float4*)&wih36[lane * 36 + 4 * q];
            float4 wiz = *(float4*)&wih36[(64 + lane) * 36 + 4 * q];
            float4 win = *(float4*)&wih36[(128 + lane) * 36 + 4 * q];
            float4 wwr = *(float4*)&whh36[lane * 36 + 4 * q];
            float4 wwz = *(float4*)&whh36[(64 + lane) * 36 + 4 * q];
            float4 wwn = *(float4*)&whh36[(128 + lane) * 36 + 4 * q];
            int kb = ch * 32 + 4 * q;
            #pragma unroll
            for (int m = 0; m < 2; ++m) {
                int jl = wave * 2 + m;
                float4 ov = *(float4*)&outjS[jl * DH + kb];  // bcast
                float4 nv = *(float4*)&newhS[jl * DH + kb];  // bcast
                gir[m] += dot4(wir, ov);
                giz[m] += dot4(wiz, ov);
                gin[m] += dot4(win, ov);
                ghr[m] += dot4(wwr, nv);
                ghz[m] += dot4(wwz, nv);
                ghn[m] += dot4(wwn, nv);
            }
        }
    }
    #pragma unroll
    for (int m = 0; m < 2; ++m) {
        int jl = wave * 2 + m;
        float r = sigf(gir[m] + bihS[lane] + ghr[m] + bhhS[lane]);
        float z = sigf(giz[m] + bihS[64 + lane] + ghz[m] + bhhS[64 + lane]);
        float n = tanhf(gin[m] + bihS[128 + lane] + r * (ghn[m] + bhhS[128 + lane]));
        float nh = newhS[jl * DH + lane];
        float uh = (1.0f - z) * n + z * nh;
        float kj = kcjS[jl];
        out[(size_t)(b * NKC + j0 + jl) * DH + lane] = (1.0f - kj) * nh + kj * uh;
    }
}

extern "C" void kernel_launch(void* const* d_in, const int* in_sizes, int n_in,
                              void* d_out, int out_size, void* d_ws, size_t ws_size,
                              hipStream_t stream) {
    const float* h        = (const float*)d_in[0];
    const float* ex       = (const float*)d_in[1];
    const float* su       = (const float*)d_in[2];
    const float* ex_graph = (const float*)d_in[3];
    const float* kc_gamma = (const float*)d_in[4];
    const float* W_ex     = (const float*)d_in[5];
    const float* W_kc     = (const float*)d_in[6];
    const float* tgru_wih = (const float*)d_in[7];
    const float* tgru_whh = (const float*)d_in[8];
    const float* tgru_bih = (const float*)d_in[9];
    const float* tgru_bhh = (const float*)d_in[10];
    const float* fpart_w  = (const float*)d_in[11];
    const float* fpart_b  = (const float*)d_in[12];
    const float* ulin_w   = (const float*)d_in[13];
    const float* ulin_b   = (const float*)d_in[14];
    const float* ugru_wih = (const float*)d_in[15];
    const float* ugru_whh = (const float*)d_in[16];
    const float* ugru_bih = (const float*)d_in[17];
    const float* ugru_bhh = (const float*)d_in[18];
    float* ws  = (float*)d_ws;
    float* out = (float*)d_out;

    hipLaunchKernelGGL(k0_x, dim3(260), dim3(256), 0, stream,
                       ex, su, W_ex, W_kc, fpart_w, fpart_b, ws);
    hipLaunchKernelGGL(k1_tgru, dim3(256), dim3(512), 0, stream,
                       h, ex, ex_graph, tgru_wih, tgru_whh, tgru_bih,
                       tgru_bhh, fpart_w, ws);
    hipLaunchKernelGGL(kB_update, dim3(256), dim3(512), 0, stream,
                       kc_gamma, ulin_w, ulin_b,
                       ugru_wih, ugru_whh, ugru_bih, ugru_bhh, ws, out);
}

// Round 10
// 126.014 us; speedup vs baseline: 1.1329x; 1.0535x over previous
//
#include <hip/hip_runtime.h>
#include <math.h>

#define NB  32
#define NKC 128
#define DH  64
#define NEX 1024
#define G3  192

// ws layout (floats)
#define XOFF    0         // 32*64   = 2048
#define KCIOFF  2048      // 32*128  = 4096
#define NHOFF   6144      // 32*128*64 = 262144   [b][i][d]
#define DPOFF   268288    // 32*64*128 = 262144   [b][d][i]  (TRANSPOSED)

__device__ __forceinline__ float sigf(float x) { return 1.0f / (1.0f + expf(-x)); }
__device__ __forceinline__ float dot4(float4 a, float4 b) {
    return fmaf(a.x, b.x, fmaf(a.y, b.y, fmaf(a.z, b.z, a.w * b.w)));
}

// ---------------------------------------------------------------------------
// k0: x only. 256 blocks (b x 8 d-chunks of 8) x 256 threads.
// ---------------------------------------------------------------------------
__global__ __launch_bounds__(256) void k0_x(
    const float* __restrict__ ex, const float* __restrict__ su,
    const float* __restrict__ W_ex, float* __restrict__ ws)
{
    int t = threadIdx.x, wave = t >> 6, lane = t & 63;
    int b = blockIdx.x >> 3;
    int dbase = (blockIdx.x & 7) * 8;
    float sub = su[b];
    const float* exb = ex + (size_t)b * NEX;
    float er[16];
    #pragma unroll
    for (int i = 0; i < 16; ++i) er[i] = exb[lane + i * 64];
    #pragma unroll
    for (int p = 0; p < 2; ++p) {
        int d = dbase + wave * 2 + p;
        const float* wr = W_ex + (size_t)d * (2 * NEX);
        float a1 = 0.f, a2 = 0.f;
        #pragma unroll
        for (int i = 0; i < 16; ++i) {
            int k = lane + i * 64;
            a1 = fmaf(er[i], wr[k], a1);
            a2 = fmaf(er[i], wr[NEX + k], a2);
        }
        float v = sub * a1 + (1.0f - sub) * a2;
        #pragma unroll
        for (int off = 32; off; off >>= 1) v += __shfl_down(v, off, 64);
        if (lane == 0) ws[XOFF + b * DH + d] = v;
    }
}

// ---------------------------------------------------------------------------
// k1: kci + gi + tgru + new_h + dpart(transposed). 256 blocks x 512 threads.
// Weights in row-major stride-36 LDS chunks -> ds_read_b128.
// ---------------------------------------------------------------------------
__global__ __launch_bounds__(512) void k1_tgru(
    const float* __restrict__ h, const float* __restrict__ ex,
    const float* __restrict__ ex_graph,
    const float* __restrict__ tgru_wih, const float* __restrict__ tgru_whh,
    const float* __restrict__ tgru_bih, const float* __restrict__ tgru_bhh,
    const float* __restrict__ fpart_w, float* __restrict__ ws)
{
    int t = threadIdx.x, wave = t >> 6, lane = t & 63;
    int b = blockIdx.x >> 3;
    int i0 = (blockIdx.x & 7) * 16;

    __shared__ __align__(16) float whh68[G3 * 36];  // reused: fw68 (64*68)
    __shared__ __align__(16) float wih68[G3 * 36];  // reused: dptT (64*17)
    __shared__ __align__(16) float ht[16 * DH];
    __shared__ __align__(16) float dlt[16 * DH];
    __shared__ __align__(16) float xs[DH];
    __shared__ float kred[512];
    __shared__ float gis[G3];
    __shared__ float bhh3[G3];
    __shared__ float kciL[16];

    // kci partials FIRST (longest-latency strided loads)
    {
        int i = t & 15, ks = t >> 4, kb = ks * 32;
        const float* exb = ex + (size_t)b * NEX;
        const float* eg = ex_graph + i0 + i;
        float a = 0.f;
        #pragma unroll 4
        for (int k = 0; k < 32; ++k)
            a = fmaf(exb[kb + k], eg[(size_t)(kb + k) * NKC], a);
        kred[t] = a;
    }
    const float* hb = h + (size_t)(b * NKC + i0) * DH;
    for (int idx = t; idx < 16 * DH; idx += 512) ht[idx] = hb[idx];
    if (t < DH) xs[t] = ws[XOFF + b * DH + t];
    if (t < G3) bhh3[t] = tgru_bhh[t];
    __syncthreads();
    if (t < 16) {
        float s = 0.f;
        #pragma unroll
        for (int r = 0; r < 32; ++r) s += kred[r * 16 + t];
        kciL[t] = s;
        ws[KCIOFF + b * NKC + i0 + t] = s;
    }

    float giA = (t < G3) ? tgru_bih[t] : 0.f;
    float ar[2], az[2], an[2];
    #pragma unroll
    for (int m = 0; m < 2; ++m) {
        ar[m] = bhh3[lane]; az[m] = bhh3[64 + lane]; an[m] = bhh3[128 + lane];
    }
    for (int ch = 0; ch < 2; ++ch) {
        __syncthreads();
        for (int idx = t; idx < G3 * 8; idx += 512) {   // 1536 float4 groups
            int row = idx >> 3, q = idx & 7;
            *(float4*)&whh68[row * 36 + 4 * q] =
                *(const float4*)&tgru_whh[row * DH + ch * 32 + 4 * q];
            *(float4*)&wih68[row * 36 + 4 * q] =
                *(const float4*)&tgru_wih[row * DH + ch * 32 + 4 * q];
        }
        __syncthreads();
        if (t < G3) {   // gi partial (wave-uniform: waves 0-2)
            #pragma unroll
            for (int q = 0; q < 8; ++q) {
                float4 wv = *(float4*)&wih68[t * 36 + 4 * q];
                float4 xv = *(float4*)&xs[ch * 32 + 4 * q];
                giA += dot4(wv, xv);
            }
        }
        #pragma unroll
        for (int q = 0; q < 8; ++q) {
            float4 wr = *(float4*)&whh68[lane * 36 + 4 * q];
            float4 wz = *(float4*)&whh68[(64 + lane) * 36 + 4 * q];
            float4 wn = *(float4*)&whh68[(128 + lane) * 36 + 4 * q];
            int kb = ch * 32 + 4 * q;
            #pragma unroll
            for (int m = 0; m < 2; ++m) {
                float4 hk = *(float4*)&ht[(wave * 2 + m) * DH + kb];  // bcast
                ar[m] += dot4(wr, hk);
                az[m] += dot4(wz, hk);
                an[m] += dot4(wn, hk);
            }
        }
    }
    if (t < G3) gis[t] = giA;
    __syncthreads();
    // GRU epilogue per i
    #pragma unroll
    for (int m = 0; m < 2; ++m) {
        int il = wave * 2 + m;
        float hval = ht[il * DH + lane];
        float r = sigf(gis[lane] + ar[m]);
        float z = sigf(gis[64 + lane] + az[m]);
        float n = tanhf(gis[128 + lane] + r * an[m]);
        float th = (1.0f - z) * n + z * hval;
        float kv = kciL[il];
        float nh = (1.0f - kv) * hval + kv * th;
        ws[NHOFF + (size_t)(b * NKC + i0 + il) * DH + lane] = nh;
        dlt[il * DH + lane] = kv * (th - hval);
    }
    __syncthreads();
    // dpart = delta_h @ fpart_w[:, :64].T ; fw68[d*68+k] row-major
    float* fw68 = whh68;   // 64*68 = 4352 <= 6912
    for (int idx = t; idx < 64 * 16; idx += 512) {
        int d = idx >> 4, q = idx & 15;
        *(float4*)&fw68[d * 68 + 4 * q] = *(const float4*)&fpart_w[d * 128 + 4 * q];
    }
    __syncthreads();
    float acc[2] = {0.f, 0.f};
    #pragma unroll
    for (int q = 0; q < 16; ++q) {
        float4 w = *(float4*)&fw68[lane * 68 + 4 * q];
        #pragma unroll
        for (int m = 0; m < 2; ++m) {
            float4 dv = *(float4*)&dlt[(wave * 2 + m) * DH + 4 * q];  // bcast
            acc[m] += dot4(w, dv);
        }
    }
    // transpose in LDS (stride 17, conflict-free), coalesced global write
    float* dptT = wih68;   // 64*17 = 1088
    __syncthreads();
    #pragma unroll
    for (int m = 0; m < 2; ++m) dptT[lane * 17 + wave * 2 + m] = acc[m];
    __syncthreads();
    for (int idx = t; idx < 1024; idx += 512) {
        int d = idx >> 4, il = idx & 15;
        ws[DPOFF + (size_t)b * 8192 + d * NKC + i0 + il] = dptT[d * 17 + il];
    }
}

// ---------------------------------------------------------------------------
// kB: epart + partj + outj + kcj + ugru + h_out. 256 blocks x 512 threads.
// All hot LDS reads are b128 (row-major padded weights / transposed dpart).
// ---------------------------------------------------------------------------
__global__ __launch_bounds__(512) void kB_update(
    const float* __restrict__ kc_gamma, const float* __restrict__ W_kc,
    const float* __restrict__ fpart_w, const float* __restrict__ fpart_b,
    const float* __restrict__ ulin_w, const float* __restrict__ ulin_b,
    const float* __restrict__ ugru_wih, const float* __restrict__ ugru_whh,
    const float* __restrict__ ugru_bih, const float* __restrict__ ugru_bhh,
    float* __restrict__ ws, float* __restrict__ out)
{
    int t = threadIdx.x, wave = t >> 6, lane = t & 63;
    int b = blockIdx.x >> 3;
    int j0 = (blockIdx.x & 7) * 16;

    __shared__ __align__(16) float scratch[13888];
    __shared__ __align__(16) float pjS[1024];
    __shared__ __align__(16) float outjS[1024];
    __shared__ __align__(16) float newhS[1024];
    __shared__ __align__(16) float epS[1024];
    __shared__ float kciF[NKC];
    __shared__ float kcjS[16];
    __shared__ float bihS[G3];
    __shared__ float bhhS[G3];

    float* dpT  = scratch;            // 64*132 = 8448   [d][i]
    float* fw68 = scratch + 8448;     // 64*68  = 4352   [d][c]
    float* wkT  = scratch + 12800;    // 16*68  = 1088   [jl][c]

    // stage dpart (global [d][i] coalesced -> LDS stride-132 rows)
    const float* dp = ws + DPOFF + (size_t)b * 8192;
    #pragma unroll
    for (int r = 0; r < 4; ++r) {
        int idx4 = t + r * 512;
        int d = idx4 >> 5, qi = idx4 & 31;
        *(float4*)&dpT[d * 132 + 4 * qi] = *(const float4*)&dp[d * NKC + 4 * qi];
    }
    for (int idx = t; idx < 64 * 16; idx += 512) {
        int d = idx >> 4, q = idx & 15;
        *(float4*)&fw68[d * 68 + 4 * q] =
            *(const float4*)&fpart_w[d * 128 + 64 + 4 * q];
    }
    for (int idx = t; idx < 1024; idx += 512) {
        int c = idx >> 4, jl = idx & 15;
        wkT[jl * 68 + c] = W_kc[(size_t)c * NKC + j0 + jl];
    }
    if (t < 256) {
        const float* nhp = ws + NHOFF + (size_t)(b * NKC + j0) * DH;
        *(float4*)&newhS[t * 4] = *(const float4*)&nhp[t * 4];
    }
    if (t < NKC) kciF[t] = ws[KCIOFF + b * NKC + t];
    if (t < G3) { bihS[t] = ugru_bih[t]; bhhS[t] = ugru_bhh[t]; }
    __syncthreads();
    // epart[jl,d] = fpart_b[d] + sum_c wk[c,jl]*fpart_w[d,64+c]
    #pragma unroll
    for (int r = 0; r < 2; ++r) {
        int idx = t + r * 512;
        int jl = idx >> 6, d = idx & 63;
        float a = fpart_b[d];
        #pragma unroll
        for (int q = 0; q < 16; ++q) {
            float4 fv = *(float4*)&fw68[d * 68 + 4 * q];
            float4 wv = *(float4*)&wkT[jl * 68 + 4 * q];
            a += dot4(fv, wv);
        }
        epS[jl * DH + d] = a;
    }
    __syncthreads();   // fw68/wkT dead
    // wj transposed [jl][i], stride 132
    float* wjT = scratch + 8448;      // 16*132 = 2112
    for (int idx = t; idx < 2048; idx += 512) {
        int i = idx >> 4, jl = idx & 15;
        wjT[jl * 132 + i] = kciF[i] * sigf(kc_gamma[i * NKC + j0 + jl]);
    }
    __syncthreads();
    if (t < 16) {
        float s = 0.f;
        #pragma unroll
        for (int qi = 0; qi < 32; ++qi) {
            float4 v = *(float4*)&wjT[t * 132 + 4 * qi];
            s += v.x + v.y + v.z + v.w;
        }
        kcjS[t] = s;
    }
    // partj: b128 dv (own row) + b128 wj broadcast
    float ep[2], pa[2];
    #pragma unroll
    for (int m = 0; m < 2; ++m) {
        ep[m] = epS[(wave * 2 + m) * DH + lane]; pa[m] = 0.f;
    }
    for (int qi = 0; qi < 32; ++qi) {
        float4 dv = *(float4*)&dpT[lane * 132 + 4 * qi];
        #pragma unroll
        for (int m = 0; m < 2; ++m) {
            float4 wv = *(float4*)&wjT[(wave * 2 + m) * 132 + 4 * qi];  // bcast
            pa[m] = fmaf(fmaxf(dv.x + ep[m], 0.f), wv.x, pa[m]);
            pa[m] = fmaf(fmaxf(dv.y + ep[m], 0.f), wv.y, pa[m]);
            pa[m] = fmaf(fmaxf(dv.z + ep[m], 0.f), wv.z, pa[m]);
            pa[m] = fmaf(fmaxf(dv.w + ep[m], 0.f), wv.w, pa[m]);
        }
    }
    #pragma unroll
    for (int m = 0; m < 2; ++m) pjS[(wave * 2 + m) * DH + lane] = pa[m];
    __syncthreads();
    // outj = relu(pj @ ulin_w.T + b); ul68[d][k] rows
    float* ul68 = scratch;            // 64*68 = 4352 (dpT dead)
    for (int idx = t; idx < 64 * 16; idx += 512) {
        int d = idx >> 4, q = idx & 15;
        *(float4*)&ul68[d * 68 + 4 * q] = *(const float4*)&ulin_w[d * DH + 4 * q];
    }
    float ulb = ulin_b[lane];
    __syncthreads();
    float oa[2] = {ulb, ulb};
    #pragma unroll
    for (int q = 0; q < 16; ++q) {
        float4 uv = *(float4*)&ul68[lane * 68 + 4 * q];
        #pragma unroll
        for (int m = 0; m < 2; ++m) {
            float4 pv = *(float4*)&pjS[(wave * 2 + m) * DH + 4 * q];  // bcast
            oa[m] += dot4(uv, pv);
        }
    }
    #pragma unroll
    for (int m = 0; m < 2; ++m)
        outjS[(wave * 2 + m) * DH + lane] = fmaxf(oa[m], 0.f);
    // ugru: k-chunked row-major stride-36 weights, b128 everywhere
    float* wih36 = scratch;           // 192*36 = 6912
    float* whh36 = scratch + 6912;    // 192*36 = 6912
    float gir[2], giz[2], gin[2], ghr[2], ghz[2], ghn[2];
    #pragma unroll
    for (int m = 0; m < 2; ++m)
        gir[m] = giz[m] = gin[m] = ghr[m] = ghz[m] = ghn[m] = 0.f;
    for (int ch = 0; ch < 2; ++ch) {
        __syncthreads();   // covers ul68/outjS deps
        for (int idx = t; idx < G3 * 8; idx += 512) {
            int row = idx >> 3, q = idx & 7;
            *(float4*)&wih36[row * 36 + 4 * q] =
                *(const float4*)&ugru_wih[row * DH + ch * 32 + 4 * q];
            *(float4*)&whh36[row * 36 + 4 * q] =
                *(const float4*)&ugru_whh[row * DH + ch * 32 + 4 * q];
        }
        __syncthreads();
        #pragma unroll
        for (int q = 0; q < 8; ++q) {
            float4 wir = *(float4*)&wih36[lane * 36 + 4 * q];
            float4 wiz = *(float4*)&wih36[(64 + lane) * 36 + 4 * q];
            float4 win = *(float4*)&wih36[(128 + lane) * 36 + 4 * q];
            float4 wwr = *(float4*)&whh36[lane * 36 + 4 * q];
            float4 wwz = *(float4*)&whh36[(64 + lane) * 36 + 4 * q];
            float4 wwn = *(float4*)&whh36[(128 + lane) * 36 + 4 * q];
            int kb = ch * 32 + 4 * q;
            #pragma unroll
            for (int m = 0; m < 2; ++m) {
                int jl = wave * 2 + m;
                float4 ov = *(float4*)&outjS[jl * DH + kb];  // bcast
                float4 nv = *(float4*)&newhS[jl * DH + kb];  // bcast
                gir[m] += dot4(wir, ov);
                giz[m] += dot4(wiz, ov);
                gin[m] += dot4(win, ov);
                ghr[m] += dot4(wwr, nv);
                ghz[m] += dot4(wwz, nv);
                ghn[m] += dot4(wwn, nv);
            }
        }
    }
    #pragma unroll
    for (int m = 0; m < 2; ++m) {
        int jl = wave * 2 + m;
        float r = sigf(gir[m] + bihS[lane] + ghr[m] + bhhS[lane]);
        float z = sigf(giz[m] + bihS[64 + lane] + ghz[m] + bhhS[64 + lane]);
        float n = tanhf(gin[m] + bihS[128 + lane] + r * (ghn[m] + bhhS[128 + lane]));
        float nh = newhS[jl * DH + lane];
        float uh = (1.0f - z) * n + z * nh;
        float kj = kcjS[jl];
        out[(size_t)(b * NKC + j0 + jl) * DH + lane] = (1.0f - kj) * nh + kj * uh;
    }
}

extern "C" void kernel_launch(void* const* d_in, const int* in_sizes, int n_in,
                              void* d_out, int out_size, void* d_ws, size_t ws_size,
                              hipStream_t stream) {
    const float* h        = (const float*)d_in[0];
    const float* ex       = (const float*)d_in[1];
    const float* su       = (const float*)d_in[2];
    const float* ex_graph = (const float*)d_in[3];
    const float* kc_gamma = (const float*)d_in[4];
    const float* W_ex     = (const float*)d_in[5];
    const float* W_kc     = (const float*)d_in[6];
    const float* tgru_wih = (const float*)d_in[7];
    const float* tgru_whh = (const float*)d_in[8];
    const float* tgru_bih = (const float*)d_in[9];
    const float* tgru_bhh = (const float*)d_in[10];
    const float* fpart_w  = (const float*)d_in[11];
    const float* fpart_b  = (const float*)d_in[12];
    const float* ulin_w   = (const float*)d_in[13];
    const float* ulin_b   = (const float*)d_in[14];
    const float* ugru_wih = (const float*)d_in[15];
    const float* ugru_whh = (const float*)d_in[16];
    const float* ugru_bih = (const float*)d_in[17];
    const float* ugru_bhh = (const float*)d_in[18];
    float* ws  = (float*)d_ws;
    float* out = (float*)d_out;

    hipLaunchKernelGGL(k0_x, dim3(256), dim3(256), 0, stream,
                       ex, su, W_ex, ws);
    hipLaunchKernelGGL(k1_tgru, dim3(256), dim3(512), 0, stream,
                       h, ex, ex_graph, tgru_wih, tgru_whh, tgru_bih,
                       tgru_bhh, fpart_w, ws);
    hipLaunchKernelGGL(kB_update, dim3(256), dim3(512), 0, stream,
                       kc_gamma, W_kc, fpart_w, fpart_b, ulin_w, ulin_b,
                       ugru_wih, ugru_whh, ugru_bih, ugru_bhh, ws, out);
}